// Round 6
// baseline (430.623 us; speedup 1.0000x reference)
//
#include <hip/hip_runtime.h>

#define PW 88
#define IS2 0.70710678118654752f

__device__ __forceinline__ int imin(int a, int b) { return a < b ? a : b; }
__device__ __forceinline__ int imax(int a, int b) { return a > b ? a : b; }

__device__ __forceinline__ int symidx(int t, int n) {
    t = (t < 0) ? (-1 - t) : t;
    return (t >= n) ? (2 * n - 1 - t) : t;
}

// barrier WITHOUT vmcnt drain: LDS ops flushed, global loads stay in flight
__device__ __forceinline__ void wg_barrier() {
    asm volatile("s_waitcnt lgkmcnt(0)" ::: "memory");
    __builtin_amdgcn_s_barrier();
    asm volatile("" ::: "memory");
}

// ---- staging: 13 clamped scalar loads of one subband plane slice / thread ----
__device__ __forceinline__ void issue_sub(float (&rc)[13], const float* __restrict__ bp,
                                          int i2lo, int i2hi, int jc, int rowpar)
{
    #pragma unroll
    for (int r = 0; r < 13; ++r) {
        int i2c = imin(i2lo + rowpar + 2 * r, i2hi);
        rc[r] = bp[i2c * 128 + jc];
    }
}

__device__ __forceinline__ void write_sub(float* sC, const float (&rc)[13],
                                          int sej, int which, int rowpar, bool sAct)
{
    if (sAct) {
        #pragma unroll
        for (int r = 0; r < 13; ++r) {
            sC[(rowpar + 2 * r) * 176 + sej * 4 + which] = rc[r];
        }
    }
}

// ---- column filter of a c2q composite read from the staged rect ----
// sC layout: [ei][ej][4] = {hrA, hrB, hiA, hiB}; b64 at +0 -> (hrA,hrB), +2 -> (hiA,hiB)
template<int L, int RO, bool BORDER>
__device__ __forceinline__ void compute_c2q(
    float* sTk, const float* sC, const float* __restrict__ taps,
    int sI, int jj, int ej, int cp, bool act, int r0, int i2lo)
{
    if (!act) return;
    constexpr int W = 8 + L - 1;
    float acc[8];
    #pragma unroll
    for (int k = 0; k < 8; ++k) acc[k] = 0.f;
    const float mO = cp ? -IS2 : IS2;
    const int laneE = ej * 4 + cp * 2;   // pairsel for even rows = cp
    const int laneO = laneE ^ 2;         // pairsel for odd rows  = cp^1
    const int rowbase = sI * 704;        // 4 rows * 176 floats
    #pragma unroll
    for (int t = 0; t < W; ++t) {
        float v;
        if (BORDER) {
            int rr = symidx(r0 - RO + 8 * sI + t, 256);
            int rp = rr & 1;
            int ei = (rr >> 1) - i2lo;
            float2 AB = *reinterpret_cast<const float2*>(&sC[ei * 176 + (rp ? laneO : laneE)]);
            v = rp ? (AB.x - AB.y) * mO : (AB.x + AB.y) * IS2;
        } else {
            const int rp  = (RO + t) & 1;            // compile-time
            const int eiC = ((t - RO) >> 1) + 5;     // compile-time (arith shift)
            float2 AB = *reinterpret_cast<const float2*>(
                &sC[rowbase + eiC * 176 + (rp ? laneO : laneE)]);
            v = rp ? (AB.x - AB.y) * mO : (AB.x + AB.y) * IS2;
        }
        #pragma unroll
        for (int k = 0; k < 8; ++k) {
            const int j = k + L - 1 - t;
            if (j >= 0 && j < L) acc[k] = fmaf(taps[j], v, acc[k]);
        }
    }
    #pragma unroll
    for (int k = 0; k < 8; ++k) sTk[(8 * sI + k) * PW + (jj + 3)] = acc[k];
}

// ---- column filter of Yl (reflection already applied at staging) ----
__device__ __forceinline__ void compute_yl(
    float* sT0, const float* sY, const float* __restrict__ g0,
    int sI, int jj, bool act)
{
    if (!act) return;
    float acc[8];
    #pragma unroll
    for (int k = 0; k < 8; ++k) acc[k] = 0.f;
    const int base = sI * 672 + jj;      // 8 rows * 84
    #pragma unroll
    for (int t = 0; t < 20; ++t) {
        float v = sY[base + t * 84];
        #pragma unroll
        for (int k = 0; k < 8; ++k) {
            const int j = k + 12 - t;
            if (j >= 0 && j < 13) acc[k] = fmaf(g0[j], v, acc[k]);
        }
    }
    #pragma unroll
    for (int k = 0; k < 8; ++k) sT0[(8 * sI + k) * PW + (jj + 3)] = acc[k];
}

extern "C" __global__ __launch_bounds__(512, 4) void dtcwt_inv(
    const float* __restrict__ Yl, const float* __restrict__ Yhr,
    const float* __restrict__ Yhi,
    const float* __restrict__ g0, const float* __restrict__ g1,
    const float* __restrict__ g2, float* __restrict__ out)
{
    __shared__ __align__(16) float sT[4][32][PW];   // 45056 B
    __shared__ __align__(16) float uB[4576];        // union: sYl[44][84] / sC[26][44][4]

    const int tid = threadIdx.x;
    // bijective XCD swizzle: 16384 = 8 x 2048
    const int wg  = blockIdx.x;
    const int swz = (wg & 7) * 2048 + (wg >> 3);
    const int plane = swz >> 5;
    const int bt = swz & 31;
    const int bx = bt & 3;
    const int by = bt >> 2;
    const int r0 = by * 32;
    const int c0 = bx * 64;

    const float* ylp = Yl  + (size_t)plane * 65536;
    const float* yhr = Yhr + (size_t)plane * 6 * 16384;
    const float* yhi = Yhi + (size_t)plane * 6 * 16384;

    // staged subband rect geometry (union of all composites' needs)
    const int rloF = imax(0, r0 - 9), rhiF = imin(255, r0 + 40);
    const int i2lo = rloF >> 1, i2hi = rhiF >> 1;
    const int clo  = imax(0, c0 - 9), chi = imin(255, c0 + 72);
    const int j2lo = clo >> 1, j2hi = chi >> 1;

    // compute-side lane constants
    const int jj = tid & 127;
    const int sI = tid >> 7;             // strip / row-group (wave-pair uniform)
    const bool act = jj < 82;
    const int ccq = symidx(c0 - 9 + jj, 256);
    const int cp  = ccq & 1;
    const int ej  = (ccq >> 1) - j2lo;

    // staging-side lane constants
    const int sej = tid & 63;
    const int which = (tid >> 6) & 3;        // wave-uniform: 0:hrA 1:hrB 2:hiA 3:hiB
    const int rowpar = (tid >> 8) & 1;       // wave-uniform
    const int jc = imin(j2lo + sej, j2hi);   // clamped subband col (always in-bounds)
    const bool sAct = sej < 42;

    const bool border = (by == 0) || (by == 7);

    const float* bpLh = ((which & 2) ? yhi : yhr) + ((which & 1) ? 5 : 0) * 16384;
    const float* bpHl = ((which & 2) ? yhi : yhr) + ((which & 1) ? 3 : 2) * 16384;
    const float* bpHh = ((which & 2) ? yhi : yhr) + ((which & 1) ? 4 : 1) * 16384;

    float rYl[11], rA[13], rB[13];

    // A) issue Yl loads (reflection applied at load; cols via ccq)
    #pragma unroll
    for (int r = 0; r < 11; ++r) {
        int rrY = symidx(r0 - 6 + sI + 4 * r, 256);
        rYl[r] = ylp[rrY * 256 + ccq];
    }
    // B) issue lh loads (bands 0,5)
    issue_sub(rA, bpLh, i2lo, i2hi, jc, rowpar);
    __builtin_amdgcn_sched_barrier(0);

    // C) write sYl, barrier (lh loads stay in flight)
    if (act) {
        #pragma unroll
        for (int r = 0; r < 11; ++r) uB[(sI + 4 * r) * 84 + jj] = rYl[r];
    }
    wg_barrier();

    // D) issue hl loads (bands 2,3)
    issue_sub(rB, bpHl, i2lo, i2hi, jc, rowpar);
    __builtin_amdgcn_sched_barrier(0);

    // E) compute Yl -> sT[0]
    compute_yl(&sT[0][0][0], uB, g0, sI, jj, act);
    wg_barrier();

    // F) write sC <- lh
    write_sub(uB, rA, sej, which, rowpar, sAct);
    wg_barrier();

    // G) issue hh loads (bands 1,4)
    issue_sub(rA, bpHh, i2lo, i2hi, jc, rowpar);
    __builtin_amdgcn_sched_barrier(0);

    // H) compute lh (g1, 19 taps) -> sT[1]
    if (border) compute_c2q<19, 9, true >(&sT[1][0][0], uB, g1, sI, jj, ej, cp, act, r0, i2lo);
    else        compute_c2q<19, 9, false>(&sT[1][0][0], uB, g1, sI, jj, ej, cp, act, r0, i2lo);
    wg_barrier();

    // I) write sC <- hl
    write_sub(uB, rB, sej, which, rowpar, sAct);
    wg_barrier();

    // J) compute hl (g0) -> sT[2]
    if (border) compute_c2q<13, 6, true >(&sT[2][0][0], uB, g0, sI, jj, ej, cp, act, r0, i2lo);
    else        compute_c2q<13, 6, false>(&sT[2][0][0], uB, g0, sI, jj, ej, cp, act, r0, i2lo);
    wg_barrier();

    // K) write sC <- hh
    write_sub(uB, rA, sej, which, rowpar, sAct);
    wg_barrier();

    // L) compute hh (g2) -> sT[3]
    if (border) compute_c2q<13, 6, true >(&sT[3][0][0], uB, g2, sI, jj, ej, cp, act, r0, i2lo);
    else        compute_c2q<13, 6, false>(&sT[3][0][0], uB, g2, sI, jj, ej, cp, act, r0, i2lo);
    wg_barrier();

    // ---------------- stage 2: row filters from LDS -> 4 outputs/thread ----------------
    const int cg = tid & 15;
    const int r  = tid >> 4;
    const int cb = 4 * cg;

    float w1[20];
    #pragma unroll
    for (int k = 0; k < 5; ++k) {
        float4 a = *(const float4*)&sT[0][r][cb + 4 + 4 * k];
        float4 b = *(const float4*)&sT[1][r][cb + 4 + 4 * k];
        w1[4*k+0] = a.x + b.x; w1[4*k+1] = a.y + b.y;
        w1[4*k+2] = a.z + b.z; w1[4*k+3] = a.w + b.w;
    }
    float w2[28];
    #pragma unroll
    for (int k = 0; k < 7; ++k) {
        float4 a = *(const float4*)&sT[2][r][cb + 4 * k];
        w2[4*k+0] = a.x; w2[4*k+1] = a.y; w2[4*k+2] = a.z; w2[4*k+3] = a.w;
    }
    float w3[20];
    #pragma unroll
    for (int k = 0; k < 5; ++k) {
        float4 a = *(const float4*)&sT[3][r][cb + 4 + 4 * k];
        w3[4*k+0] = a.x; w3[4*k+1] = a.y; w3[4*k+2] = a.z; w3[4*k+3] = a.w;
    }

    float4 res;
    float* rp = (float*)&res;
    #pragma unroll
    for (int q = 0; q < 4; ++q) {
        float sacc = 0.0f;
        #pragma unroll
        for (int j = 0; j < 13; ++j) sacc = fmaf(g0[j], w1[q + 14 - j], sacc);
        #pragma unroll
        for (int j = 0; j < 19; ++j) sacc = fmaf(g1[j], w2[q + 21 - j], sacc);
        #pragma unroll
        for (int j = 0; j < 13; ++j) sacc = fmaf(g2[j], w3[q + 14 - j], sacc);
        rp[q] = sacc;
    }
    *(float4*)&out[(size_t)plane * 65536 + (size_t)(r0 + r) * 256 + (c0 + cb)] = res;
}

extern "C" void kernel_launch(void* const* d_in, const int* in_sizes, int n_in,
                              void* d_out, int out_size, void* d_ws, size_t ws_size,
                              hipStream_t stream) {
    const float* Yl  = (const float*)d_in[0];
    const float* Yhr = (const float*)d_in[1];
    const float* Yhi = (const float*)d_in[2];
    const float* g0  = (const float*)d_in[3];
    const float* g1  = (const float*)d_in[4];
    const float* g2  = (const float*)d_in[5];
    float* out = (float*)d_out;

    dim3 grid(16384, 1, 1);
    dim3 block(512, 1, 1);
    dtcwt_inv<<<grid, block, 0, stream>>>(Yl, Yhr, Yhi, g0, g1, g2, out);
}

// Round 7
// 386.152 us; speedup vs baseline: 1.1152x; 1.1152x over previous
//
#include <hip/hip_runtime.h>

#define PW 90
#define IS2 0.70710678118654752f

__device__ __forceinline__ int imin(int a, int b) { return a < b ? a : b; }
__device__ __forceinline__ int imax(int a, int b) { return a > b ? a : b; }

__device__ __forceinline__ int symidx(int t, int n) {
    t = (t < 0) ? (-1 - t) : t;
    return (t >= n) ? (2 * n - 1 - t) : t;
}

// barrier WITHOUT vmcnt drain: LDS ops flushed, global loads stay in flight
__device__ __forceinline__ void wg_barrier() {
    asm volatile("s_waitcnt lgkmcnt(0)" ::: "memory");
    __builtin_amdgcn_s_barrier();
    asm volatile("" ::: "memory");
}

// ---- staging: 13 clamped scalar loads of one subband plane slice / thread ----
__device__ __forceinline__ void issue_sub(float (&rc)[13], const float* __restrict__ bp,
                                          int i2lo, int i2hi, int jc, int rowpar)
{
    #pragma unroll
    for (int r = 0; r < 13; ++r) {
        int i2c = imin(i2lo + rowpar + 2 * r, i2hi);
        rc[r] = bp[i2c * 128 + jc];
    }
}

// layout: uB[ei][plane(4)][ej(44)] ; plane order 0:hrA 1:hrB 2:hiA 3:hiB
__device__ __forceinline__ void write_sub(float* uB, const float (&rc)[13],
                                          int sej, int which, int rowpar, bool sAct)
{
    if (sAct) {
        #pragma unroll
        for (int r = 0; r < 13; ++r)
            uB[(rowpar + 2 * r) * 176 + which * 44 + sej] = rc[r];
    }
}

// ---- column filter of a c2q composite from staged rect, 8-row strip ----
// even rows read feed-pair fp=cp (A at +0, B at +44); odd rows fp=cp^1.
template<int L, int RO, bool BORDER>
__device__ __forceinline__ void compute_c2q(
    float* sTk, const float* uB, const float* __restrict__ taps,
    int sI, int jj, int ej, int cp, bool act, int r0, int i2lo)
{
    if (!act) return;
    float acc[8];
    #pragma unroll
    for (int k = 0; k < 8; ++k) acc[k] = 0.f;
    const float sgnO = cp ? -IS2 : IS2;
    const int be = (cp ? 88 : 0) + ej;      // even-row base (dwords)
    const int bo = (cp ? 0 : 88) + ej;      // odd-row base
    const int beS = be + sI * 704;          // + strip offset (4sI rows * 176)
    const int boS = bo + sI * 704;
    #pragma unroll
    for (int tl = 0; tl < 8 + L - 1; ++tl) {
        float v;
        if (BORDER) {
            int rr = symidx(r0 + 8 * sI + tl - RO, 256);   // wave-uniform
            int rp = rr & 1;
            int ei = (rr >> 1) - i2lo;
            int ba = ei * 176 + (rp ? bo : be);
            float A = uB[ba], B = uB[ba + 44];
            v = rp ? (A - B) * sgnO : (A + B) * IS2;
        } else {
            const int rp  = (tl - RO) & 1;                 // compile-time
            const int eib = ((tl - RO) >> 1) + 5;          // compile-time
            int ba = eib * 176 + (rp ? boS : beS);         // immediate + base reg
            float A = uB[ba], B = uB[ba + 44];
            v = rp ? (A - B) * sgnO : (A + B) * IS2;
        }
        #pragma unroll
        for (int k = 0; k < 8; ++k) {
            const int j = k + (L - 1) - tl;
            if (j >= 0 && j < L) acc[k] = fmaf(taps[j], v, acc[k]);
        }
    }
    #pragma unroll
    for (int k = 0; k < 8; ++k) sTk[(8 * sI + k) * PW + jj + 3] = acc[k];
}

// ---- column filter of Yl (reflection applied at staging), 8-row strip ----
__device__ __forceinline__ void compute_yl(
    float* sT0, const float* uB, const float* __restrict__ g0,
    int sI, int jy, bool act)
{
    if (!act) return;
    float acc[8];
    #pragma unroll
    for (int k = 0; k < 8; ++k) acc[k] = 0.f;
    const int base = 8 * sI * 80 + jy;
    #pragma unroll
    for (int tl = 0; tl < 20; ++tl) {
        float v = uB[base + tl * 80];
        #pragma unroll
        for (int k = 0; k < 8; ++k) {
            const int j = k + 12 - tl;
            if (j >= 0 && j < 13) acc[k] = fmaf(g0[j], v, acc[k]);
        }
    }
    #pragma unroll
    for (int k = 0; k < 8; ++k) sT0[(8 * sI + k) * PW + jy + 6] = acc[k];
}

extern "C" __global__ __launch_bounds__(512, 4) void dtcwt_inv(
    const float* __restrict__ Yl, const float* __restrict__ Yhr,
    const float* __restrict__ Yhi,
    const float* __restrict__ g0, const float* __restrict__ g1,
    const float* __restrict__ g2, float* __restrict__ out)
{
    __shared__ __align__(16) float sT[4][32][PW];   // 46080 B
    __shared__ __align__(16) float uB[4608];        // 18432 B: sYl[44][80] / sC[26][4][44]

    const int tid = threadIdx.x;
    // bijective XCD swizzle: 16384 = 8 x 2048
    const int wg  = blockIdx.x;
    const int swz = (wg & 7) * 2048 + (wg >> 3);
    const int plane = swz >> 5;
    const int bt = swz & 31;
    const int bx = bt & 3;
    const int by = bt >> 2;
    const int r0 = by * 32;
    const int c0 = bx * 64;

    const float* ylp = Yl  + (size_t)plane * 65536;
    const float* yhr = Yhr + (size_t)plane * 6 * 16384;
    const float* yhi = Yhi + (size_t)plane * 6 * 16384;

    // staged subband rect
    const int i2lo = imax(0, r0 - 9) >> 1;
    const int i2hi = imin(255, r0 + 40) >> 1;
    const int j2lo = imax(0, c0 - 9) >> 1;
    const int j2hi = imin(255, c0 + 72) >> 1;

    // compute-side constants
    const int sI = tid >> 7;                 // strip (wave-pair uniform)
    const int jj = tid & 127;
    const bool actC = jj < 82;
    const int ccq = symidx(c0 - 9 + jj, 256);
    const int cp  = ccq & 1;
    const int ej  = (ccq >> 1) - j2lo;
    const bool actY = jj < 76;
    const int ccY = symidx(c0 - 6 + jj, 256);

    // staging-side constants
    const int sej = tid & 63;
    const int which = (tid >> 6) & 3;
    const int rowpar = (tid >> 8) & 1;
    const int jc = imin(j2lo + sej, j2hi);
    const bool sAct = sej < 42;

    const bool borderR = (by == 0) || (by == 7);

    const float* bpLh = ((which & 2) ? yhi : yhr) + ((which & 1) ? 5 : 0) * 16384;
    const float* bpHl = ((which & 2) ? yhi : yhr) + ((which & 1) ? 3 : 2) * 16384;
    const float* bpHh = ((which & 2) ? yhi : yhr) + ((which & 1) ? 4 : 1) * 16384;

    float rYl[11], rA[13], rB[13];

    // P1: issue Yl + lh loads
    #pragma unroll
    for (int s = 0; s < 11; ++s) {
        int rrY = symidx(r0 - 6 + sI + 4 * s, 256);
        rYl[s] = ylp[rrY * 256 + ccY];
    }
    issue_sub(rA, bpLh, i2lo, i2hi, jc, rowpar);
    __builtin_amdgcn_sched_barrier(0);

    // P2: write Yl to uB
    if (actY) {
        #pragma unroll
        for (int s = 0; s < 11; ++s) uB[(sI + 4 * s) * 80 + jj] = rYl[s];
    }
    wg_barrier();

    // P3: issue hl; compute Yl -> sT[0]
    issue_sub(rB, bpHl, i2lo, i2hi, jc, rowpar);
    __builtin_amdgcn_sched_barrier(0);
    compute_yl(&sT[0][0][0], uB, g0, sI, jj, actY);
    wg_barrier();

    // P4: write lh
    write_sub(uB, rA, sej, which, rowpar, sAct);
    wg_barrier();

    // P5: issue hh; compute lh (g1, 19 taps) -> sT[1]
    issue_sub(rA, bpHh, i2lo, i2hi, jc, rowpar);
    __builtin_amdgcn_sched_barrier(0);
    if (borderR) compute_c2q<19, 9, true >(&sT[1][0][0], uB, g1, sI, jj, ej, cp, actC, r0, i2lo);
    else         compute_c2q<19, 9, false>(&sT[1][0][0], uB, g1, sI, jj, ej, cp, actC, r0, i2lo);
    wg_barrier();

    // P6: write hl
    write_sub(uB, rB, sej, which, rowpar, sAct);
    wg_barrier();

    // P7: compute hl (g0) -> sT[2]
    if (borderR) compute_c2q<13, 6, true >(&sT[2][0][0], uB, g0, sI, jj, ej, cp, actC, r0, i2lo);
    else         compute_c2q<13, 6, false>(&sT[2][0][0], uB, g0, sI, jj, ej, cp, actC, r0, i2lo);
    wg_barrier();

    // P8: write hh
    write_sub(uB, rA, sej, which, rowpar, sAct);
    wg_barrier();

    // P9: compute hh (g2) -> sT[3]
    if (borderR) compute_c2q<13, 6, true >(&sT[3][0][0], uB, g2, sI, jj, ej, cp, actC, r0, i2lo);
    else         compute_c2q<13, 6, false>(&sT[3][0][0], uB, g2, sI, jj, ej, cp, actC, r0, i2lo);
    wg_barrier();

    // ---------------- stage 2: row filters (float2, PW=90) ----------------
    const int cg = tid & 15;
    const int r2 = tid >> 4;
    const int cb = 4 * cg;

    float w1[20];
    #pragma unroll
    for (int k = 0; k < 10; ++k) {
        float2 a = *(const float2*)&sT[0][r2][cb + 4 + 2 * k];
        float2 b = *(const float2*)&sT[1][r2][cb + 4 + 2 * k];
        w1[2*k]   = a.x + b.x;
        w1[2*k+1] = a.y + b.y;
    }
    float w2[28];
    #pragma unroll
    for (int k = 0; k < 14; ++k) {
        float2 a = *(const float2*)&sT[2][r2][cb + 2 * k];
        w2[2*k] = a.x; w2[2*k+1] = a.y;
    }
    float w3[20];
    #pragma unroll
    for (int k = 0; k < 10; ++k) {
        float2 a = *(const float2*)&sT[3][r2][cb + 4 + 2 * k];
        w3[2*k] = a.x; w3[2*k+1] = a.y;
    }

    float4 res;
    float* op = (float*)&res;
    #pragma unroll
    for (int q = 0; q < 4; ++q) {
        float s = 0.0f;
        #pragma unroll
        for (int j = 0; j < 13; ++j) s = fmaf(g0[j], w1[q + 14 - j], s);
        #pragma unroll
        for (int j = 0; j < 19; ++j) s = fmaf(g1[j], w2[q + 21 - j], s);
        #pragma unroll
        for (int j = 0; j < 13; ++j) s = fmaf(g2[j], w3[q + 14 - j], s);
        op[q] = s;
    }
    *(float4*)&out[(size_t)plane * 65536 + (size_t)(r0 + r2) * 256 + (c0 + cb)] = res;
}

extern "C" void kernel_launch(void* const* d_in, const int* in_sizes, int n_in,
                              void* d_out, int out_size, void* d_ws, size_t ws_size,
                              hipStream_t stream) {
    const float* Yl  = (const float*)d_in[0];
    const float* Yhr = (const float*)d_in[1];
    const float* Yhi = (const float*)d_in[2];
    const float* g0  = (const float*)d_in[3];
    const float* g1  = (const float*)d_in[4];
    const float* g2  = (const float*)d_in[5];
    float* out = (float*)d_out;

    dim3 grid(16384, 1, 1);
    dim3 block(512, 1, 1);
    dtcwt_inv<<<grid, block, 0, stream>>>(Yl, Yhr, Yhi, g0, g1, g2, out);
}

// Round 8
// 308.245 us; speedup vs baseline: 1.3970x; 1.2527x over previous
//
#include <hip/hip_runtime.h>

#define PW 90
#define IS2 0.70710678118654752f

__device__ __forceinline__ int symidx(int t, int n) {
    t = (t < 0) ? (-1 - t) : t;
    return (t >= n) ? (2 * n - 1 - t) : t;
}

#define SB() __builtin_amdgcn_sched_barrier(0)

// ================= border-path helpers (r1, proven) =================
__device__ __forceinline__ void col13_yl(
    float (&acc)[32], const float* __restrict__ ylp,
    const float* __restrict__ taps, int r0, int cc)
{
    #pragma unroll
    for (int pi = 0; pi < 44; ++pi) {
        int rr = symidx(r0 - 6 + pi, 256);
        float v = ylp[rr * 256 + cc];
        #pragma unroll
        for (int j = 0; j < 13; ++j) {
            int ro = pi + j - 12;
            if (ro >= 0 && ro < 32) acc[ro] = fmaf(taps[j], v, acc[ro]);
        }
    }
}

__device__ __forceinline__ void col13_c2q(
    float (&acc)[32], const float* __restrict__ yhr, const float* __restrict__ yhi,
    int bA, int bB, const float* __restrict__ taps, int r0, int cc)
{
    const int cp = cc & 1;
    const int j2 = cc >> 1;
    #pragma unroll
    for (int pi = 0; pi < 44; ++pi) {
        int rr = symidx(r0 - 6 + pi, 256);
        int rp = rr & 1;
        int i2 = rr >> 1;
        const float* base = (((rp ^ cp) != 0) ? yhi : yhr) + (i2 * 128 + j2);
        float A  = base[bA * 16384];
        float Bv = base[bB * 16384];
        float vA = (rp & cp)       ? -A  : A;
        float vB = (rp & (cp ^ 1)) ? -Bv : Bv;
        float v = (vA + vB) * IS2;
        #pragma unroll
        for (int j = 0; j < 13; ++j) {
            int ro = pi + j - 12;
            if (ro >= 0 && ro < 32) acc[ro] = fmaf(taps[j], v, acc[ro]);
        }
    }
}

__device__ __forceinline__ void col19_c2q(
    float (&acc)[32], const float* __restrict__ yhr, const float* __restrict__ yhi,
    const float* __restrict__ taps, int r0, int cc)
{
    const int bA = 0, bB = 5;
    const int cp = cc & 1;
    const int j2 = cc >> 1;
    #pragma unroll
    for (int pi = 0; pi < 50; ++pi) {
        int rr = symidx(r0 - 9 + pi, 256);
        int rp = rr & 1;
        int i2 = rr >> 1;
        const float* base = (((rp ^ cp) != 0) ? yhi : yhr) + (i2 * 128 + j2);
        float A  = base[bA * 16384];
        float Bv = base[bB * 16384];
        float vA = (rp & cp)       ? -A  : A;
        float vB = (rp & (cp ^ 1)) ? -Bv : Bv;
        float v = (vA + vB) * IS2;
        #pragma unroll
        for (int j = 0; j < 19; ++j) {
            int ro = pi + j - 18;
            if (ro >= 0 && ro < 32) acc[ro] = fmaf(taps[j], v, acc[ro]);
        }
    }
}

// ================= interior pipelined helpers =================
// load NU row-pairs (4 floats each) starting at global pair index UB
template<int NU>
__device__ __forceinline__ void load_pairs(float (&buf)[28],
    const float* __restrict__ pEA, const float* __restrict__ pEB,
    const float* __restrict__ pOA, const float* __restrict__ pOB,
    int vof)
{
    #pragma unroll
    for (int u = 0; u < NU; ++u) {
        buf[4*u+0] = pEA[vof + u * 128];
        buf[4*u+1] = pEB[vof + u * 128];
        buf[4*u+2] = pOA[vof + u * 128];
        buf[4*u+3] = pOB[vof + u * 128];
    }
}

// consume NU pairs with global pair indices UB..UB+NU-1
template<int L, int EPI0, int UB, int NU>
__device__ __forceinline__ void consume_pairs(float (&acc)[32], const float (&buf)[28],
                                              float sgn, const float* __restrict__ taps)
{
    #pragma unroll
    for (int u = 0; u < NU; ++u) {
        float ve = (buf[4*u+0] + buf[4*u+1]) * IS2;
        float vo = (buf[4*u+2] - buf[4*u+3]) * sgn;
        const int pi = EPI0 + 2 * (UB + u);
        #pragma unroll
        for (int j = 0; j < L; ++j) {
            int ro = pi + j - (L - 1);
            if (ro >= 0 && ro < 32) acc[ro] = fmaf(taps[j], ve, acc[ro]);
        }
        #pragma unroll
        for (int j = 0; j < L; ++j) {
            int ro = pi + 1 + j - (L - 1);
            if (ro >= 0 && ro < 32) acc[ro] = fmaf(taps[j], vo, acc[ro]);
        }
    }
}

template<int NT>
__device__ __forceinline__ void load_rows(float (&buf)[11], const float* __restrict__ p, int t0)
{
    #pragma unroll
    for (int t = 0; t < NT; ++t) buf[t] = p[(t0 + t) * 256];
}

template<int TB, int NT>
__device__ __forceinline__ void consume_rows(float (&acc)[32], const float (&buf)[11],
                                             const float* __restrict__ taps)
{
    #pragma unroll
    for (int t = 0; t < NT; ++t) {
        float v = buf[t];
        const int pi = TB + t;
        #pragma unroll
        for (int j = 0; j < 13; ++j) {
            int ro = pi + j - 12;
            if (ro >= 0 && ro < 32) acc[ro] = fmaf(taps[j], v, acc[ro]);
        }
    }
}

// pipelined c2q column filter: NPT total pairs in chunks of C,C,C,rest
template<int L, int EPI0, int NPT, int C>
__device__ __forceinline__ void c2q_col_pipe(
    float (&acc)[32],
    const float* __restrict__ pEA, const float* __restrict__ pEB,
    const float* __restrict__ pOA, const float* __restrict__ pOB,
    int vof, float sgn, const float* __restrict__ taps)
{
    float bufA[28], bufB[28];
    constexpr int R = NPT - 3 * C;     // last chunk
    load_pairs<C>(bufA, pEA, pEB, pOA, pOB, vof);
    SB();
    load_pairs<C>(bufB, pEA, pEB, pOA, pOB, vof + C * 128);
    SB();
    consume_pairs<L, EPI0, 0, C>(acc, bufA, sgn, taps);
    SB();
    load_pairs<C>(bufA, pEA, pEB, pOA, pOB, vof + 2 * C * 128);
    SB();
    consume_pairs<L, EPI0, C, C>(acc, bufB, sgn, taps);
    SB();
    load_pairs<R>(bufB, pEA, pEB, pOA, pOB, vof + 3 * C * 128);
    SB();
    consume_pairs<L, EPI0, 2 * C, C>(acc, bufA, sgn, taps);
    SB();
    consume_pairs<L, EPI0, 3 * C, R>(acc, bufB, sgn, taps);
}

extern "C" __global__ __launch_bounds__(512, 4) void dtcwt_inv(
    const float* __restrict__ Yl, const float* __restrict__ Yhr,
    const float* __restrict__ Yhi,
    const float* __restrict__ g0, const float* __restrict__ g1,
    const float* __restrict__ g2, float* __restrict__ out)
{
    __shared__ __align__(16) float sT[4][32][PW];   // 46080 B

    const int tid = threadIdx.x;
    // bijective XCD swizzle: 16384 = 8 x 2048
    const int wg  = blockIdx.x;
    const int swz = (wg & 7) * 2048 + (wg >> 3);
    const int plane = swz >> 5;
    const int bt = swz & 31;
    const int bx = bt & 3;
    const int by = bt >> 2;
    const int r0 = by * 32;
    const int c0 = bx * 64;

    const float* ylp = Yl  + (size_t)plane * 65536;
    const float* yhr = Yhr + (size_t)plane * 6 * 16384;
    const float* yhi = Yhi + (size_t)plane * 6 * 16384;

    const bool rowInterior = (by >= 1) && (by <= 6);

    const int role = tid >> 7;
    const int lr   = tid & 127;

    float acc[32];
    #pragma unroll
    for (int i = 0; i < 32; ++i) acc[i] = 0.0f;
    int ti = -1;

    if (rowInterior) {
        if (role == 0) {
            if (lr < 76) {
                ti = lr + 6;
                int cc = symidx(c0 + lr - 6, 256);
                const float* p = ylp + (r0 - 6) * 256 + cc;
                float bufA[11], bufB[11];
                load_rows<11>(bufA, p, 0);
                SB();
                load_rows<11>(bufB, p, 11);
                SB();
                consume_rows<0, 11>(acc, bufA, g0);
                SB();
                load_rows<11>(bufA, p, 22);
                SB();
                consume_rows<11, 11>(acc, bufB, g0);
                SB();
                load_rows<11>(bufB, p, 33);
                SB();
                consume_rows<22, 11>(acc, bufA, g0);
                SB();
                consume_rows<33, 11>(acc, bufB, g0);
            }
        } else if (role == 1) {
            if (lr < 76) {                        // t1b = col_g1(lh), bands 0,5
                ti = lr + 6;
                int cc = symidx(c0 + lr - 6, 256);
                int cp = cc & 1, j2 = cc >> 1;
                const float* pE = cp ? yhi : yhr;
                const float* pO = cp ? yhr : yhi;
                float sgn = cp ? -IS2 : IS2;
                int vof = ((r0 - 10) >> 1) * 128 + j2;
                c2q_col_pipe<19, -1, 26, 7>(acc,
                    pE + 0 * 16384, pE + 5 * 16384,
                    pO + 0 * 16384, pO + 5 * 16384, vof, sgn, g1);
            }
        } else if (role == 2) {
            if (lr < 82) {                        // t2 = col_g0(hl), bands 2,3
                ti = lr + 3;
                int cc = symidx(c0 + lr - 9, 256);
                int cp = cc & 1, j2 = cc >> 1;
                const float* pE = cp ? yhi : yhr;
                const float* pO = cp ? yhr : yhi;
                float sgn = cp ? -IS2 : IS2;
                int vof = ((r0 - 6) >> 1) * 128 + j2;
                c2q_col_pipe<13, 0, 22, 6>(acc,
                    pE + 2 * 16384, pE + 3 * 16384,
                    pO + 2 * 16384, pO + 3 * 16384, vof, sgn, g0);
            }
        } else {
            if (lr < 76) {                        // t3 = col_g2(hh), bands 1,4
                ti = lr + 6;
                int cc = symidx(c0 + lr - 6, 256);
                int cp = cc & 1, j2 = cc >> 1;
                const float* pE = cp ? yhi : yhr;
                const float* pO = cp ? yhr : yhi;
                float sgn = cp ? -IS2 : IS2;
                int vof = ((r0 - 6) >> 1) * 128 + j2;
                c2q_col_pipe<13, 0, 22, 6>(acc,
                    pE + 1 * 16384, pE + 4 * 16384,
                    pO + 1 * 16384, pO + 4 * 16384, vof, sgn, g2);
            }
        }
    } else {
        // ---------- border stage 1 (r1 path, handles row reflection) ----------
        if (role == 0) {
            if (lr < 76) {
                ti = lr + 6;
                int cc = symidx(c0 + ti - 12, 256);
                col13_yl(acc, ylp, g0, r0, cc);
            }
        } else if (role == 1) {
            if (lr < 76) {
                ti = lr + 6;
                int cc = symidx(c0 + ti - 12, 256);
                col19_c2q(acc, yhr, yhi, g1, r0, cc);
            }
        } else if (role == 2) {
            if (lr < 82) {
                ti = lr + 3;
                int cc = symidx(c0 + ti - 12, 256);
                col13_c2q(acc, yhr, yhi, 2, 3, g0, r0, cc);
            }
        } else {
            if (lr < 76) {
                ti = lr + 6;
                int cc = symidx(c0 + ti - 12, 256);
                col13_c2q(acc, yhr, yhi, 1, 4, g2, r0, cc);
            }
        }
    }
    if (ti >= 0) {
        #pragma unroll
        for (int ro = 0; ro < 32; ++ro) sT[role][ro][ti] = acc[ro];
    }
    __syncthreads();

    // ---------------- stage 2: row filters (float2, PW=90) ----------------
    const int cg = tid & 15;
    const int r2 = tid >> 4;
    const int cb = 4 * cg;

    float w1[20];
    #pragma unroll
    for (int k = 0; k < 10; ++k) {
        float2 a = *(const float2*)&sT[0][r2][cb + 4 + 2 * k];
        float2 b = *(const float2*)&sT[1][r2][cb + 4 + 2 * k];
        w1[2*k]   = a.x + b.x;
        w1[2*k+1] = a.y + b.y;
    }
    float w2[28];
    #pragma unroll
    for (int k = 0; k < 14; ++k) {
        float2 a = *(const float2*)&sT[2][r2][cb + 2 * k];
        w2[2*k] = a.x; w2[2*k+1] = a.y;
    }
    float w3[20];
    #pragma unroll
    for (int k = 0; k < 10; ++k) {
        float2 a = *(const float2*)&sT[3][r2][cb + 4 + 2 * k];
        w3[2*k] = a.x; w3[2*k+1] = a.y;
    }

    float4 res;
    float* op = (float*)&res;
    #pragma unroll
    for (int q = 0; q < 4; ++q) {
        float s = 0.0f;
        #pragma unroll
        for (int j = 0; j < 13; ++j) s = fmaf(g0[j], w1[q + 14 - j], s);
        #pragma unroll
        for (int j = 0; j < 19; ++j) s = fmaf(g1[j], w2[q + 21 - j], s);
        #pragma unroll
        for (int j = 0; j < 13; ++j) s = fmaf(g2[j], w3[q + 14 - j], s);
        op[q] = s;
    }
    *(float4*)&out[(size_t)plane * 65536 + (size_t)(r0 + r2) * 256 + (c0 + cb)] = res;
}

extern "C" void kernel_launch(void* const* d_in, const int* in_sizes, int n_in,
                              void* d_out, int out_size, void* d_ws, size_t ws_size,
                              hipStream_t stream) {
    const float* Yl  = (const float*)d_in[0];
    const float* Yhr = (const float*)d_in[1];
    const float* Yhi = (const float*)d_in[2];
    const float* g0  = (const float*)d_in[3];
    const float* g1  = (const float*)d_in[4];
    const float* g2  = (const float*)d_in[5];
    float* out = (float*)d_out;

    dim3 grid(16384, 1, 1);
    dim3 block(512, 1, 1);
    dtcwt_inv<<<grid, block, 0, stream>>>(Yl, Yhr, Yhi, g0, g1, g2, out);
}